// Round 11
// baseline (274.045 us; speedup 1.0000x reference)
//
#include <hip/hip_runtime.h>
#include <math.h>

#define NTOK 8192
#define HD   2048
#define OD   1024
#define NE   8
#define CTXD 4096
#define CH   64

typedef short bf16x8 __attribute__((ext_vector_type(8)));
typedef float f32x4  __attribute__((ext_vector_type(4)));

static const size_t OFF_VN = (size_t)NTOK * OD;                 // v_next
static const size_t OFF_RP = 2 * (size_t)NTOK * OD;             // router_probs
static const size_t OFF_TI = OFF_RP + (size_t)NTOK * NE;        // top_k_idx
static const size_t OFF_TP = OFF_TI + (size_t)NTOK * 2;         // top_k_probs

// ---- ws byte offsets ----
#define WS_PCNT   0
#define WS_TOTAL  256
#define WS_TABLE  512
#define WS_PLIST  8192
#define WS_PWTS   (8192 + 64*NTOK*4)
#define WS_W1P    (WS_PWTS + 64*NTOK*8)
#define WS_W2P    (WS_W1P + NE*CTXD*CH*2)
#define WS_CTXB   (WS_W2P + NE*CH*3*OD*2)
#define WS_NEED2  ((size_t)WS_CTXB + (size_t)NTOK*CTXD*2)   // + 64 MB ctx bf16

__device__ __forceinline__ unsigned bfpack2(float a, float b) {
    unsigned ua = __float_as_uint(a), ub = __float_as_uint(b);
    ua = (ua + 0x7FFFu + ((ua >> 16) & 1u)) >> 16;
    ub = (ub + 0x7FFFu + ((ub >> 16) & 1u)) >> 16;
    return ua | (ub << 16);
}
__device__ __forceinline__ float fsigmoid(float z) {
    return __fdividef(1.f, 1.f + __expf(-z));
}
__device__ __forceinline__ float fsoftplus(float z) {
    return fmaxf(z, 0.f) + __logf(1.f + __expf(-fabsf(z)));
}

// ---------------- fused pre-pass: convert W1 | convert W2 | ctx->bf16 + router
// blocks [0,1024): W1 -> W1p [8][512][64][8]
// blocks [1024,1792): W2 -> W2p [8][8][3072][8]
// blocks [1792,1792+8192): one token each: ctx bf16 convert + fused router
__global__ __launch_bounds__(256) void pre_kernel(
    const float* __restrict__ h, const float* __restrict__ x,
    const float* __restrict__ v, const float* __restrict__ rw,
    const float* __restrict__ rb,
    const float* __restrict__ W1, const float* __restrict__ W2,
    unsigned short* __restrict__ W1p, unsigned short* __restrict__ W2p,
    unsigned short* __restrict__ ctxb,
    float* __restrict__ out,
    int* __restrict__ pcnt, int* __restrict__ plist, float2* __restrict__ pwts)
{
    __shared__ float rpart[128][8];              // router partials (4 KB)
    int bb = blockIdx.x;
    int tid = threadIdx.x;
    if (bb < 1024) {
        int flat = bb * 256 + tid;
        int e = flat >> 15, rem = flat & 32767;
        int kb = rem >> 6, c = rem & 63;
        const float* src = W1 + (size_t)e * CTXD * CH + (size_t)kb * 8 * CH + c;
        uint4 o;
        o.x = bfpack2(src[0 * 64], src[1 * 64]);
        o.y = bfpack2(src[2 * 64], src[3 * 64]);
        o.z = bfpack2(src[4 * 64], src[5 * 64]);
        o.w = bfpack2(src[6 * 64], src[7 * 64]);
        *(uint4*)(W1p + (size_t)flat * 8) = o;
        return;
    }
    if (bb < 1792) {
        int flat = (bb - 1024) * 256 + tid;
        int e = flat / 24576, rem = flat - e * 24576;
        int kb = rem / 3072, c = rem - kb * 3072;
        const float* src = W2 + ((size_t)e * CH + kb * 8) * (3 * OD) + c;
        uint4 o;
        o.x = bfpack2(src[0 * 3072], src[1 * 3072]);
        o.y = bfpack2(src[2 * 3072], src[3 * 3072]);
        o.z = bfpack2(src[4 * 3072], src[5 * 3072]);
        o.w = bfpack2(src[6 * 3072], src[7 * 3072]);
        *(uint4*)(W2p + (size_t)flat * 8) = o;
        return;
    }
    // ---- ctx -> bf16 (one token row) + fused router ----
    int t = bb - 1792;
    int col = tid * 16;
    const float* src;
    if (col < HD)           src = h + (size_t)t * HD + col;
    else if (col < HD + OD) src = x + (size_t)t * OD + (col - HD);
    else                    src = v + (size_t)t * OD + (col - HD - OD);
    float4 f0 = ((const float4*)src)[0];
    float4 f1 = ((const float4*)src)[1];
    float4 f2 = ((const float4*)src)[2];
    float4 f3 = ((const float4*)src)[3];
    {
        uint4 o0, o1;
        o0.x = bfpack2(f0.x, f0.y); o0.y = bfpack2(f0.z, f0.w);
        o0.z = bfpack2(f1.x, f1.y); o0.w = bfpack2(f1.z, f1.w);
        o1.x = bfpack2(f2.x, f2.y); o1.y = bfpack2(f2.z, f2.w);
        o1.z = bfpack2(f3.x, f3.y); o1.w = bfpack2(f3.z, f3.w);
        uint4* dst = (uint4*)(ctxb + (size_t)t * CTXD + col);
        dst[0] = o0; dst[1] = o1;
    }
    // router partials: threads 0..127 hold the h row (cols 0..2047)
    if (tid < 128) {
        float hv[16] = {f0.x,f0.y,f0.z,f0.w, f1.x,f1.y,f1.z,f1.w,
                        f2.x,f2.y,f2.z,f2.w, f3.x,f3.y,f3.z,f3.w};
        float r0=0.f,r1=0.f,r2=0.f,r3=0.f,r4=0.f,r5=0.f,r6=0.f,r7=0.f;
        #pragma unroll
        for (int j = 0; j < 16; j++) {
            const float4* wr = (const float4*)(rw + (size_t)(col + j) * 8);
            float4 wa = wr[0], wb = wr[1];
            r0 = fmaf(hv[j], wa.x, r0); r1 = fmaf(hv[j], wa.y, r1);
            r2 = fmaf(hv[j], wa.z, r2); r3 = fmaf(hv[j], wa.w, r3);
            r4 = fmaf(hv[j], wb.x, r4); r5 = fmaf(hv[j], wb.y, r5);
            r6 = fmaf(hv[j], wb.z, r6); r7 = fmaf(hv[j], wb.w, r7);
        }
        *(float4*)&rpart[tid][0] = make_float4(r0, r1, r2, r3);
        *(float4*)&rpart[tid][4] = make_float4(r4, r5, r6, r7);
    }
    __syncthreads();
    if (tid < 64) {
        float a0 = rpart[tid][0] + rpart[tid+64][0];
        float a1 = rpart[tid][1] + rpart[tid+64][1];
        float a2 = rpart[tid][2] + rpart[tid+64][2];
        float a3 = rpart[tid][3] + rpart[tid+64][3];
        float a4 = rpart[tid][4] + rpart[tid+64][4];
        float a5 = rpart[tid][5] + rpart[tid+64][5];
        float a6 = rpart[tid][6] + rpart[tid+64][6];
        float a7 = rpart[tid][7] + rpart[tid+64][7];
        #pragma unroll
        for (int off = 32; off >= 1; off >>= 1) {
            a0 += __shfl_xor(a0, off); a1 += __shfl_xor(a1, off);
            a2 += __shfl_xor(a2, off); a3 += __shfl_xor(a3, off);
            a4 += __shfl_xor(a4, off); a5 += __shfl_xor(a5, off);
            a6 += __shfl_xor(a6, off); a7 += __shfl_xor(a7, off);
        }
        if (tid == 0) {
            float lg[8] = {a0+rb[0], a1+rb[1], a2+rb[2], a3+rb[3],
                           a4+rb[4], a5+rb[5], a6+rb[6], a7+rb[7]};
            float m = lg[0];
            #pragma unroll
            for (int e2 = 1; e2 < 8; e2++) m = fmaxf(m, lg[e2]);
            float p[8]; float s = 0.f;
            #pragma unroll
            for (int e2 = 0; e2 < 8; e2++) { p[e2] = expf(lg[e2] - m); s += p[e2]; }
            float inv = 1.f / s;
            #pragma unroll
            for (int e2 = 0; e2 < 8; e2++) {
                p[e2] *= inv;
                out[OFF_RP + (size_t)t * 8 + e2] = p[e2];
            }
            int e0 = 0;
            #pragma unroll
            for (int e2 = 1; e2 < 8; e2++) if (p[e2] > p[e0]) e0 = e2;
            int e1 = (e0 == 0) ? 1 : 0;
            #pragma unroll
            for (int e2 = 0; e2 < 8; e2++) {
                if (e2 == e0) continue;
                if (p[e2] > p[e1]) e1 = e2;
            }
            float s2 = p[e0] + p[e1];
            float w0 = p[e0] / s2, w1 = p[e1] / s2;
            out[OFF_TI + (size_t)t*2 + 0] = (float)e0;
            out[OFF_TI + (size_t)t*2 + 1] = (float)e1;
            out[OFF_TP + (size_t)t*2 + 0] = w0;
            out[OFF_TP + (size_t)t*2 + 1] = w1;
            int lo = min(e0, e1), hi = max(e0, e1);
            float wlo = (e0 < e1) ? w0 : w1;
            float whi = (e0 < e1) ? w1 : w0;
            int pid = lo * 8 + hi;
            int pos = atomicAdd(&pcnt[pid], 1);
            plist[pid * NTOK + pos] = t;
            pwts[pid * NTOK + pos] = make_float2(wlo, whi);
        }
    }
}

// ---------------- prefix: pid counts -> dense 16-token tile table
__global__ void prefix_kernel(const int* __restrict__ pcnt,
                              int* __restrict__ table, int* __restrict__ total) {
    int tid = threadIdx.x;
    int cnt = pcnt[tid];
    int tiles = (cnt + 15) >> 4;
    int incl = tiles;
    #pragma unroll
    for (int off = 1; off < 64; off <<= 1) {
        int v = __shfl_up(incl, off);
        if (tid >= off) incl += v;
    }
    int base = incl - tiles;
    for (int i = 0; i < tiles; i++) table[base + i] = tid | (i << 6);
    if (tid == 63) *total = incl;
}

// ---------------- MoE: PRECONV=1 reads bf16 ctxb; PRECONV=0 packs in-loop
template<bool PRECONV>
__global__ __launch_bounds__(512, 4) void moe_t(
    const float* __restrict__ h, const float* __restrict__ x,
    const float* __restrict__ v, const float* __restrict__ mu,
    const float* __restrict__ b1, const float* __restrict__ b2,
    const unsigned short* __restrict__ W1p, const unsigned short* __restrict__ W2p,
    const unsigned short* __restrict__ ctxb,
    const int* __restrict__ pcnt, const int* __restrict__ table,
    const int* __restrict__ total, const int* __restrict__ plist,
    const float2* __restrict__ pwts, float* __restrict__ out)
{
    __shared__ float part[16][64][8];            // 32 KB
    __shared__ unsigned short hid_s[16 * 128];   // 4 KB
    __shared__ int    toks[16];
    __shared__ float2 tw[16];

    int bid = (blockIdx.x & 7) * 72 + (blockIdx.x >> 3);   // XCD-chunked, 576=8*72
    if (bid >= *total) return;
    int entry = table[bid];
    int pid = entry & 63;
    int start = (entry >> 6) * 16;
    int lo = pid >> 3, hi = pid & 7;
    int cnt = pcnt[pid];
    int nt = cnt - start; if (nt > 16) nt = 16;

    int tid = threadIdx.x;
    if (tid < 16) {
        int idx = start + (tid < nt ? tid : 0);
        toks[tid] = plist[pid * NTOK + idx];
        tw[tid]   = pwts[pid * NTOK + idx];
    }
    __syncthreads();

    int lane = tid & 63, w = tid >> 6;           // 8 waves
    int l15 = lane & 15, lq = lane >> 4;

    // ---- stage 1: wave = (expert slot, K-quarter); 16 tok x 64 col
    {
        int s1s = w >> 2;
        int kq  = w & 3;
        int myE = s1s ? hi : lo;
        const unsigned short* W1e = W1p + (size_t)myE * (CTXD * CH);
        int tokA = toks[l15];

        f32x4 acc[4];
        #pragma unroll
        for (int cg = 0; cg < 4; cg++) acc[cg] = (f32x4){0.f,0.f,0.f,0.f};

        if constexpr (PRECONV) {
            const unsigned short* base = ctxb + (size_t)tokA * CTXD + kq * 1024;
            // depth-4 rotating A-frag pipeline (fully static under unroll)
            bf16x8 ap[4][4];
            #pragma unroll
            for (int c = 0; c < 4; c++)
                #pragma unroll
                for (int ks = 0; ks < 4; ks++)
                    ap[c][ks] = *(const bf16x8*)(base + c * 128 + ks * 32 + lq * 8);
            #pragma unroll
            for (int c = 0; c < 8; c++) {
                bf16x8 a0 = ap[c & 3][0], a1 = ap[c & 3][1],
                       a2 = ap[c & 3][2], a3 = ap[c & 3][3];
                if (c < 4) {
                    #pragma unroll
                    for (int ks = 0; ks < 4; ks++)
                        ap[c][ks] = *(const bf16x8*)(base + (c + 4) * 128 + ks * 32 + lq * 8);
                }
                #pragma unroll
                for (int ks = 0; ks < 4; ks++) {
                    bf16x8 av = (ks == 0) ? a0 : (ks == 1) ? a1 : (ks == 2) ? a2 : a3;
                    int kb = kq * 128 + c * 16 + ks * 4 + lq;
                    const unsigned short* wp = W1e + (size_t)kb * 512;
                    #pragma unroll
                    for (int cg = 0; cg < 4; cg++) {
                        bf16x8 bfr = *(const bf16x8*)(wp + (size_t)(cg * 16 + l15) * 8);
                        acc[cg] = __builtin_amdgcn_mfma_f32_16x16x32_bf16(av, bfr, acc[cg], 0, 0, 0);
                    }
                }
            }
        } else {
            const float* base;
            if (kq < 2)       base = h + (size_t)tokA * HD + kq * 1024;
            else if (kq == 2) base = x + (size_t)tokA * OD;
            else              base = v + (size_t)tokA * OD;
            #pragma unroll 2
            for (int c = 0; c < 8; c++) {
                const float* cb = base + c * 128;
                bf16x8 a[4];
                #pragma unroll
                for (int ks = 0; ks < 4; ks++) {
                    const float4* s = (const float4*)(cb + ks * 32 + lq * 8);
                    float4 g0 = s[0], g1 = s[1];
                    uint4 pk;
                    pk.x = bfpack2(g0.x, g0.y);
                    pk.y = bfpack2(g0.z, g0.w);
                    pk.z = bfpack2(g1.x, g1.y);
                    pk.w = bfpack2(g1.z, g1.w);
                    a[ks] = __builtin_bit_cast(bf16x8, pk);
                }
                #pragma unroll
                for (int ks = 0; ks < 4; ks++) {
                    int kb = kq * 128 + c * 16 + ks * 4 + lq;
                    const unsigned short* wp = W1e + (size_t)kb * 512;
                    #pragma unroll
                    for (int cg = 0; cg < 4; cg++) {
                        bf16x8 bfr = *(const bf16x8*)(wp + (size_t)(cg * 16 + l15) * 8);
                        acc[cg] = __builtin_amdgcn_mfma_f32_16x16x32_bf16(a[ks], bfr, acc[cg], 0, 0, 0);
                    }
                }
            }
        }

        #pragma unroll
        for (int cg = 0; cg < 4; cg++)
            #pragma unroll
            for (int i = 0; i < 4; i++)
                part[lq * 4 + i][cg * 16 + l15][s1s * 4 + kq] = acc[cg][i];
    }
    __syncthreads();

    // ---- reduce: 512 thr -> 2048 hid values (sum 4 kq + bias + relu -> bf16)
    {
        int rs   = tid >> 8;
        int rtok = (tid >> 4) & 15;
        int rc4  = (tid & 15) * 4;
        int eS = rs ? hi : lo;
        float sm[4];
        #pragma unroll
        for (int j = 0; j < 4; j++) {
            f32x4 p = *(const f32x4*)&part[rtok][rc4 + j][rs * 4];
            float sv = p[0] + p[1] + p[2] + p[3] + b1[eS * CH + rc4 + j];
            sm[j] = sv > 0.f ? sv : 0.f;
        }
        uint2 u = make_uint2(bfpack2(sm[0], sm[1]), bfpack2(sm[2], sm[3]));
        int byte = (rtok * 256 + (rs * 64 + rc4) * 2) ^ ((rtok & 7) << 4);
        *(uint2*)((char*)hid_s + byte) = u;
    }
    __syncthreads();

    // ---- stage 2: wave w owns o-band [w*128, w*128+128)
    bf16x8 af[2][2];
    #pragma unroll
    for (int s = 0; s < 2; s++)
        #pragma unroll
        for (int ks = 0; ks < 2; ks++) {
            int col = s * 64 + ks * 32 + lq * 8;
            int by = (l15 * 256 + col * 2) ^ ((l15 & 7) << 4);
            af[s][ks] = *(const bf16x8*)((const char*)hid_s + by);
        }

    const unsigned short* W2lo = W2p + (size_t)lo * (CH * 3 * OD);
    const unsigned short* W2hi = W2p + (size_t)hi * (CH * 3 * OD);
    const float* b2lo = b2 + (size_t)lo * 3072;
    const float* b2hi = b2 + (size_t)hi * 3072;

    int   tok_r[4];
    float twx[4], twy[4];
    #pragma unroll
    for (int i = 0; i < 4; i++) {
        int trow = lq * 4 + i;
        tok_r[i] = toks[trow];
        float2 t2 = tw[trow];
        twx[i] = t2.x; twy[i] = t2.y;
    }

    #pragma unroll 2
    for (int ot = 0; ot < 8; ot++) {
        int o = w * 128 + ot * 16 + l15;
        float xo[4], vo[4];
        #pragma unroll
        for (int i = 0; i < 4; i++) {
            size_t off = (size_t)tok_r[i] * OD + o;
            xo[i] = x[off];
            vo[i] = v[off];
        }
        float muo = mu[o];
        float accVN[4] = {0.f,0.f,0.f,0.f};
        float accGV[4] = {0.f,0.f,0.f,0.f};

        #pragma unroll
        for (int s = 0; s < 2; s++) {
            const unsigned short* W2e = s ? W2hi : W2lo;
            const float* b2e = s ? b2hi : b2lo;
            f32x4 aA = {0.f,0.f,0.f,0.f};
            f32x4 aB = {0.f,0.f,0.f,0.f};
            f32x4 aG = {0.f,0.f,0.f,0.f};
            #pragma unroll
            for (int ks = 0; ks < 2; ks++) {
                int kb = ks * 4 + lq;
                bf16x8 wA = *(const bf16x8*)(W2e + ((size_t)kb * 3072 + o) * 8);
                bf16x8 wB = *(const bf16x8*)(W2e + ((size_t)kb * 3072 + OD + o) * 8);
                bf16x8 wG = *(const bf16x8*)(W2e + ((size_t)kb * 3072 + 2 * OD + o) * 8);
                aA = __builtin_amdgcn_mfma_f32_16x16x32_bf16(af[s][ks], wA, aA, 0, 0, 0);
                aB = __builtin_amdgcn_mfma_f32_16x16x32_bf16(af[s][ks], wB, aB, 0, 0, 0);
                aG = __builtin_amdgcn_mfma_f32_16x16x32_bf16(af[s][ks], wG, aG, 0, 0, 0);
            }
            float ba = b2e[o], bb = b2e[OD + o], bg = b2e[2 * OD + o];
            #pragma unroll
            for (int i = 0; i < 4; i++) {
                float za = aA[i] + ba;
                float zb = aB[i] + bb;
                float zg = aG[i] + bg;
                float alpha = fsigmoid(za);
                float beta  = fsoftplus(zb);
                float gate  = fsigmoid(zg);
                float ws = s ? twy[i] : twx[i];
                float vn_s = alpha * vo[i] - beta * (xo[i] - muo);
                accVN[i] += ws * vn_s;
                accGV[i] += ws * gate * vn_s;
            }
        }
        #pragma unroll
        for (int i = 0; i < 4; i++) {
            if (lq * 4 + i < nt) {
                size_t off = (size_t)tok_r[i] * OD + o;
                out[off]          = xo[i] + 0.1f * accGV[i];
                out[OFF_VN + off] = accVN[i];
            }
        }
    }
}

extern "C" void kernel_launch(void* const* d_in, const int* in_sizes, int n_in,
                              void* d_out, int out_size, void* d_ws, size_t ws_size,
                              hipStream_t stream)
{
    (void)in_sizes; (void)n_in; (void)out_size;
    const float* h  = (const float*)d_in[0];
    const float* x  = (const float*)d_in[1];
    const float* v  = (const float*)d_in[2];
    const float* rw = (const float*)d_in[3];
    const float* rb = (const float*)d_in[4];
    const float* mu = (const float*)d_in[5];
    const float* W1 = (const float*)d_in[6];
    const float* b1 = (const float*)d_in[7];
    const float* W2 = (const float*)d_in[8];
    const float* b2 = (const float*)d_in[9];
    float* out = (float*)d_out;

    char* ws = (char*)d_ws;
    int*    pcnt  = (int*)(ws + WS_PCNT);
    int*    total = (int*)(ws + WS_TOTAL);
    int*    table = (int*)(ws + WS_TABLE);
    int*    plist = (int*)(ws + WS_PLIST);
    float2* pwts  = (float2*)(ws + WS_PWTS);
    unsigned short* W1p  = (unsigned short*)(ws + WS_W1P);
    unsigned short* W2p  = (unsigned short*)(ws + WS_W2P);
    unsigned short* ctxb = (unsigned short*)(ws + WS_CTXB);

    bool preconv = (ws_size >= WS_NEED2);

    hipMemsetAsync(pcnt, 0, 64 * sizeof(int), stream);

    pre_kernel<<<1792 + NTOK, 256, 0, stream>>>(h, x, v, rw, rb, W1, W2,
                                                W1p, W2p, ctxb, out,
                                                pcnt, plist, pwts);
    prefix_kernel<<<1, 64, 0, stream>>>(pcnt, table, total);

    if (preconv) {
        moe_t<true><<<576, 512, 0, stream>>>(h, x, v, mu, b1, b2, W1p, W2p, ctxb,
                                             pcnt, table, total, plist, pwts, out);
    } else {
        moe_t<false><<<576, 512, 0, stream>>>(h, x, v, mu, b1, b2, W1p, W2p, ctxb,
                                              pcnt, table, total, plist, pwts, out);
    }
}

// Round 12
// 208.110 us; speedup vs baseline: 1.3168x; 1.3168x over previous
//
#include <hip/hip_runtime.h>
#include <math.h>

#define NTOK 8192
#define HD   2048
#define OD   1024
#define NE   8
#define CTXD 4096
#define CH   64

typedef short bf16x8 __attribute__((ext_vector_type(8)));
typedef float f32x4  __attribute__((ext_vector_type(4)));

static const size_t OFF_VN = (size_t)NTOK * OD;                 // v_next
static const size_t OFF_RP = 2 * (size_t)NTOK * OD;             // router_probs
static const size_t OFF_TI = OFF_RP + (size_t)NTOK * NE;        // top_k_idx
static const size_t OFF_TP = OFF_TI + (size_t)NTOK * 2;         // top_k_probs

// ---- ws byte offsets ----
#define WS_PCNT   0
#define WS_TOTAL  256
#define WS_TABLE  512
#define WS_PLIST  8192
#define WS_PWTS   (8192 + 64*NTOK*4)
#define WS_W1P    (WS_PWTS + 64*NTOK*8)
#define WS_W2P    (WS_W1P + NE*CTXD*CH*2)
#define WS_CTXB   (WS_W2P + NE*CH*3*OD*2)

__device__ __forceinline__ unsigned bfpack2(float a, float b) {
    unsigned ua = __float_as_uint(a), ub = __float_as_uint(b);
    ua = (ua + 0x7FFFu + ((ua >> 16) & 1u)) >> 16;
    ub = (ub + 0x7FFFu + ((ub >> 16) & 1u)) >> 16;
    return ua | (ub << 16);
}
__device__ __forceinline__ unsigned short bf1(float a) {
    unsigned ua = __float_as_uint(a);
    return (unsigned short)((ua + 0x7FFFu + ((ua >> 16) & 1u)) >> 16);
}
__device__ __forceinline__ float fsigmoid(float z) {
    return __fdividef(1.f, 1.f + __expf(-z));
}
__device__ __forceinline__ float fsoftplus(float z) {
    return fmaxf(z, 0.f) + __logf(1.f + __expf(-fabsf(z)));
}
__device__ __forceinline__ void gl_lds16(const void* g, void* l) {
    __builtin_amdgcn_global_load_lds(
        (const __attribute__((address_space(1))) void*)g,
        (__attribute__((address_space(3))) void*)l, 16, 0, 0);
}

// ---------------- fused pre-pass: convert W1 | convert W2 | ctx->bf16 + router
__global__ __launch_bounds__(256) void pre_kernel(
    const float* __restrict__ h, const float* __restrict__ x,
    const float* __restrict__ v, const float* __restrict__ rw,
    const float* __restrict__ rb,
    const float* __restrict__ W1, const float* __restrict__ W2,
    unsigned short* __restrict__ W1p, unsigned short* __restrict__ W2p,
    unsigned short* __restrict__ ctxb,
    float* __restrict__ out,
    int* __restrict__ pcnt, int* __restrict__ plist, float2* __restrict__ pwts)
{
    __shared__ float rpart[128][8];              // router partials (4 KB)
    int bb = blockIdx.x;
    int tid = threadIdx.x;
    if (bb < 1024) {
        int flat = bb * 256 + tid;
        int e = flat >> 15, rem = flat & 32767;
        int kb = rem >> 6, c = rem & 63;
        const float* src = W1 + (size_t)e * CTXD * CH + (size_t)kb * 8 * CH + c;
        uint4 o;
        o.x = bfpack2(src[0 * 64], src[1 * 64]);
        o.y = bfpack2(src[2 * 64], src[3 * 64]);
        o.z = bfpack2(src[4 * 64], src[5 * 64]);
        o.w = bfpack2(src[6 * 64], src[7 * 64]);
        *(uint4*)(W1p + (size_t)flat * 8) = o;
        return;
    }
    if (bb < 1792) {
        int flat = (bb - 1024) * 256 + tid;
        int e = flat / 24576, rem = flat - e * 24576;
        int kb = rem / 3072, c = rem - kb * 3072;
        const float* src = W2 + ((size_t)e * CH + kb * 8) * (3 * OD) + c;
        uint4 o;
        o.x = bfpack2(src[0 * 3072], src[1 * 3072]);
        o.y = bfpack2(src[2 * 3072], src[3 * 3072]);
        o.z = bfpack2(src[4 * 3072], src[5 * 3072]);
        o.w = bfpack2(src[6 * 3072], src[7 * 3072]);
        *(uint4*)(W2p + (size_t)flat * 8) = o;
        return;
    }
    // ---- ctx -> bf16 (one token row) + fused router ----
    int t = bb - 1792;
    int col = tid * 16;
    const float* src;
    if (col < HD)           src = h + (size_t)t * HD + col;
    else if (col < HD + OD) src = x + (size_t)t * OD + (col - HD);
    else                    src = v + (size_t)t * OD + (col - HD - OD);
    float4 f0 = ((const float4*)src)[0];
    float4 f1 = ((const float4*)src)[1];
    float4 f2 = ((const float4*)src)[2];
    float4 f3 = ((const float4*)src)[3];
    {
        uint4 o0, o1;
        o0.x = bfpack2(f0.x, f0.y); o0.y = bfpack2(f0.z, f0.w);
        o0.z = bfpack2(f1.x, f1.y); o0.w = bfpack2(f1.z, f1.w);
        o1.x = bfpack2(f2.x, f2.y); o1.y = bfpack2(f2.z, f2.w);
        o1.z = bfpack2(f3.x, f3.y); o1.w = bfpack2(f3.z, f3.w);
        uint4* dst = (uint4*)(ctxb + (size_t)t * CTXD + col);
        dst[0] = o0; dst[1] = o1;
    }
    // router partials: threads 0..127 hold the h row (cols 0..2047)
    if (tid < 128) {
        float hv[16] = {f0.x,f0.y,f0.z,f0.w, f1.x,f1.y,f1.z,f1.w,
                        f2.x,f2.y,f2.z,f2.w, f3.x,f3.y,f3.z,f3.w};
        float r0=0.f,r1=0.f,r2=0.f,r3=0.f,r4=0.f,r5=0.f,r6=0.f,r7=0.f;
        #pragma unroll
        for (int j = 0; j < 16; j++) {
            const float4* wr = (const float4*)(rw + (size_t)(col + j) * 8);
            float4 wa = wr[0], wb = wr[1];
            r0 = fmaf(hv[j], wa.x, r0); r1 = fmaf(hv[j], wa.y, r1);
            r2 = fmaf(hv[j], wa.z, r2); r3 = fmaf(hv[j], wa.w, r3);
            r4 = fmaf(hv[j], wb.x, r4); r5 = fmaf(hv[j], wb.y, r5);
            r6 = fmaf(hv[j], wb.z, r6); r7 = fmaf(hv[j], wb.w, r7);
        }
        *(float4*)&rpart[tid][0] = make_float4(r0, r1, r2, r3);
        *(float4*)&rpart[tid][4] = make_float4(r4, r5, r6, r7);
    }
    __syncthreads();
    if (tid < 64) {
        float a0 = rpart[tid][0] + rpart[tid+64][0];
        float a1 = rpart[tid][1] + rpart[tid+64][1];
        float a2 = rpart[tid][2] + rpart[tid+64][2];
        float a3 = rpart[tid][3] + rpart[tid+64][3];
        float a4 = rpart[tid][4] + rpart[tid+64][4];
        float a5 = rpart[tid][5] + rpart[tid+64][5];
        float a6 = rpart[tid][6] + rpart[tid+64][6];
        float a7 = rpart[tid][7] + rpart[tid+64][7];
        #pragma unroll
        for (int off = 32; off >= 1; off >>= 1) {
            a0 += __shfl_xor(a0, off); a1 += __shfl_xor(a1, off);
            a2 += __shfl_xor(a2, off); a3 += __shfl_xor(a3, off);
            a4 += __shfl_xor(a4, off); a5 += __shfl_xor(a5, off);
            a6 += __shfl_xor(a6, off); a7 += __shfl_xor(a7, off);
        }
        if (tid == 0) {
            float lg[8] = {a0+rb[0], a1+rb[1], a2+rb[2], a3+rb[3],
                           a4+rb[4], a5+rb[5], a6+rb[6], a7+rb[7]};
            float m = lg[0];
            #pragma unroll
            for (int e2 = 1; e2 < 8; e2++) m = fmaxf(m, lg[e2]);
            float p[8]; float s = 0.f;
            #pragma unroll
            for (int e2 = 0; e2 < 8; e2++) { p[e2] = expf(lg[e2] - m); s += p[e2]; }
            float inv = 1.f / s;
            #pragma unroll
            for (int e2 = 0; e2 < 8; e2++) {
                p[e2] *= inv;
                out[OFF_RP + (size_t)t * 8 + e2] = p[e2];
            }
            int e0 = 0;
            #pragma unroll
            for (int e2 = 1; e2 < 8; e2++) if (p[e2] > p[e0]) e0 = e2;
            int e1 = (e0 == 0) ? 1 : 0;
            #pragma unroll
            for (int e2 = 0; e2 < 8; e2++) {
                if (e2 == e0) continue;
                if (p[e2] > p[e1]) e1 = e2;
            }
            float s2 = p[e0] + p[e1];
            float w0 = p[e0] / s2, w1 = p[e1] / s2;
            out[OFF_TI + (size_t)t*2 + 0] = (float)e0;
            out[OFF_TI + (size_t)t*2 + 1] = (float)e1;
            out[OFF_TP + (size_t)t*2 + 0] = w0;
            out[OFF_TP + (size_t)t*2 + 1] = w1;
            int lo = min(e0, e1), hi = max(e0, e1);
            float wlo = (e0 < e1) ? w0 : w1;
            float whi = (e0 < e1) ? w1 : w0;
            int pid = lo * 8 + hi;
            int pos = atomicAdd(&pcnt[pid], 1);
            plist[pid * NTOK + pos] = t;
            pwts[pid * NTOK + pos] = make_float2(wlo, whi);
        }
    }
}

// ---------------- prefix: pid counts -> dense 16-token tile table
__global__ void prefix_kernel(const int* __restrict__ pcnt,
                              int* __restrict__ table, int* __restrict__ total) {
    int tid = threadIdx.x;
    int cnt = pcnt[tid];
    int tiles = (cnt + 15) >> 4;
    int incl = tiles;
    #pragma unroll
    for (int off = 1; off < 64; off <<= 1) {
        int v = __shfl_up(incl, off);
        if (tid >= off) incl += v;
    }
    int base = incl - tiles;
    for (int i = 0; i < tiles; i++) table[base + i] = tid | (i << 6);
    if (tid == 63) *total = incl;
}

// ---------------- MoE: global_load_lds double-buffered stage-1, full-K acc
__global__ __launch_bounds__(512, 4) void moe_kernel(
    const float* __restrict__ x, const float* __restrict__ v,
    const float* __restrict__ mu,
    const float* __restrict__ b1, const float* __restrict__ b2,
    const unsigned short* __restrict__ W1p, const unsigned short* __restrict__ W2p,
    const unsigned short* __restrict__ ctxb,
    const int* __restrict__ pcnt, const int* __restrict__ table,
    const int* __restrict__ total, const int* __restrict__ plist,
    const float2* __restrict__ pwts, float* __restrict__ out)
{
    __shared__ unsigned short abuf[2][8192];     // dbuf A-tile chunk 16tok x 512c (2x16KB)
    __shared__ unsigned short hid_s[16 * 128];   // swizzled bf16 [16 tok][2*64]  4 KB
    __shared__ int    toks[16];
    __shared__ float2 tw[16];

    int bid = (blockIdx.x & 7) * 72 + (blockIdx.x >> 3);   // XCD-chunked, 576=8*72
    if (bid >= *total) return;
    int entry = table[bid];
    int pid = entry & 63;
    int start = (entry >> 6) * 16;
    int lo = pid >> 3, hi = pid & 7;
    int cnt = pcnt[pid];
    int nt = cnt - start; if (nt > 16) nt = 16;

    int tid = threadIdx.x;
    if (tid < 16) {
        int idx = start + (tid < nt ? tid : 0);
        toks[tid] = plist[pid * NTOK + idx];
        tw[tid]   = pwts[pid * NTOK + idx];
    }
    __syncthreads();

    int lane = tid & 63, w = tid >> 6;           // 8 waves
    int l15 = lane & 15, lq = lane >> 4;

    // stage-1 wave roles: (expert slot, col-group); full-K accumulation
    int s1s = w >> 2;                            // 0 = lo, 1 = hi
    int cg  = w & 3;                             // 16-col group within expert's 64
    int myE = s1s ? hi : lo;
    int colw = cg * 16 + l15;
    const unsigned short* W1e = W1p + (size_t)myE * (CTXD * CH);

    // staging: per chunk (512 cols), wave w stages token rows 2w, 2w+1
    // LDS linear; global src pre-swizzled so reads can XOR-deswizzle (rule #21)
    int wv2 = w * 2;

#define STAGE(KC, BUF) do {                                                    \
        _Pragma("unroll")                                                      \
        for (int j = 0; j < 2; j++) {                                          \
            int r_ = wv2 + j;                                                  \
            int tok_ = toks[r_];                                               \
            int soff_ = ((lane * 16) ^ ((r_ & 7) << 4)) >> 1;                  \
            const unsigned short* gs_ = ctxb + (size_t)tok_ * CTXD             \
                                        + (KC) * 512 + soff_;                  \
            gl_lds16(gs_, (char*)abuf[BUF] + w * 2048 + j * 1024);             \
        }                                                                      \
    } while (0)

    f32x4 acc = {0.f, 0.f, 0.f, 0.f};

    STAGE(0, 0);
    __syncthreads();                              // vmcnt drain -> buf0 ready
    for (int kc = 0; kc < 8; kc++) {
        int cur = kc & 1;
        if (kc < 7) STAGE(kc + 1, cur ^ 1);       // async DMA, hides under compute
        #pragma unroll
        for (int ks = 0; ks < 16; ks++) {
            int phys = (ks * 64 + lq * 16) ^ ((l15 & 7) << 4);
            bf16x8 a = *(const bf16x8*)((const char*)abuf[cur] + l15 * 1024 + phys);
            int kb = kc * 64 + ks * 4 + lq;
            bf16x8 b = *(const bf16x8*)(W1e + ((size_t)kb * 64 + colw) * 8);
            acc = __builtin_amdgcn_mfma_f32_16x16x32_bf16(a, b, acc, 0, 0, 0);
        }
        __syncthreads();                          // drains stage DMA + guards dbuf
    }
#undef STAGE

    // relu + bias -> hid LDS (bf16, swizzled). C layout: col=l15, row=lq*4+i
    {
        float b1v = b1[myE * CH + colw];
        int colh = s1s * 64 + colw;
        #pragma unroll
        for (int i = 0; i < 4; i++) {
            int r0 = lq * 4 + i;
            float hv = acc[i] + b1v; hv = hv > 0.f ? hv : 0.f;
            int by = (r0 * 256 + colh * 2) ^ ((r0 & 7) << 4);
            *(unsigned short*)((char*)hid_s + by) = bf1(hv);
        }
    }
    __syncthreads();

    // ---- stage 2: wave w owns o-band [w*128, w*128+128)
    bf16x8 af[2][2];
    #pragma unroll
    for (int s = 0; s < 2; s++)
        #pragma unroll
        for (int ks = 0; ks < 2; ks++) {
            int col = s * 64 + ks * 32 + lq * 8;
            int by = (l15 * 256 + col * 2) ^ ((l15 & 7) << 4);
            af[s][ks] = *(const bf16x8*)((const char*)hid_s + by);
        }

    const unsigned short* W2lo = W2p + (size_t)lo * (CH * 3 * OD);
    const unsigned short* W2hi = W2p + (size_t)hi * (CH * 3 * OD);
    const float* b2lo = b2 + (size_t)lo * 3072;
    const float* b2hi = b2 + (size_t)hi * 3072;

    int   tok_r[4];
    float twx[4], twy[4];
    #pragma unroll
    for (int i = 0; i < 4; i++) {
        int trow = lq * 4 + i;
        tok_r[i] = toks[trow];
        float2 t2 = tw[trow];
        twx[i] = t2.x; twy[i] = t2.y;
    }

    for (int ot = 0; ot < 8; ot++) {
        int o = w * 128 + ot * 16 + l15;
        float xo[4], vo[4];
        #pragma unroll
        for (int i = 0; i < 4; i++) {
            size_t off = (size_t)tok_r[i] * OD + o;
            xo[i] = x[off];
            vo[i] = v[off];
        }
        float muo = mu[o];
        float accVN[4] = {0.f,0.f,0.f,0.f};
        float accGV[4] = {0.f,0.f,0.f,0.f};

        #pragma unroll
        for (int s = 0; s < 2; s++) {
            const unsigned short* W2e = s ? W2hi : W2lo;
            const float* b2e = s ? b2hi : b2lo;
            f32x4 aA = {0.f,0.f,0.f,0.f};
            f32x4 aB = {0.f,0.f,0.f,0.f};
            f32x4 aG = {0.f,0.f,0.f,0.f};
            #pragma unroll
            for (int ks = 0; ks < 2; ks++) {
                int kb = ks * 4 + lq;
                bf16x8 wA = *(const bf16x8*)(W2e + ((size_t)kb * 3072 + o) * 8);
                bf16x8 wB = *(const bf16x8*)(W2e + ((size_t)kb * 3072 + OD + o) * 8);
                bf16x8 wG = *(const bf16x8*)(W2e + ((size_t)kb * 3072 + 2 * OD + o) * 8);
                aA = __builtin_amdgcn_mfma_f32_16x16x32_bf16(af[s][ks], wA, aA, 0, 0, 0);
                aB = __builtin_amdgcn_mfma_f32_16x16x32_bf16(af[s][ks], wB, aB, 0, 0, 0);
                aG = __builtin_amdgcn_mfma_f32_16x16x32_bf16(af[s][ks], wG, aG, 0, 0, 0);
            }
            float ba = b2e[o], bb = b2e[OD + o], bg = b2e[2 * OD + o];
            #pragma unroll
            for (int i = 0; i < 4; i++) {
                float za = aA[i] + ba;
                float zb = aB[i] + bb;
                float zg = aG[i] + bg;
                float alpha = fsigmoid(za);
                float beta  = fsoftplus(zb);
                float gate  = fsigmoid(zg);
                float ws = s ? twy[i] : twx[i];
                float vn_s = alpha * vo[i] - beta * (xo[i] - muo);
                accVN[i] += ws * vn_s;
                accGV[i] += ws * gate * vn_s;
            }
        }
        #pragma unroll
        for (int i = 0; i < 4; i++) {
            if (lq * 4 + i < nt) {
                size_t off = (size_t)tok_r[i] * OD + o;
                out[off]          = xo[i] + 0.1f * accGV[i];
                out[OFF_VN + off] = accVN[i];
            }
        }
    }
}

extern "C" void kernel_launch(void* const* d_in, const int* in_sizes, int n_in,
                              void* d_out, int out_size, void* d_ws, size_t ws_size,
                              hipStream_t stream)
{
    (void)in_sizes; (void)n_in; (void)out_size; (void)ws_size;
    const float* h  = (const float*)d_in[0];
    const float* x  = (const float*)d_in[1];
    const float* v  = (const float*)d_in[2];
    const float* rw = (const float*)d_in[3];
    const float* rb = (const float*)d_in[4];
    const float* mu = (const float*)d_in[5];
    const float* W1 = (const float*)d_in[6];
    const float* b1 = (const float*)d_in[7];
    const float* W2 = (const float*)d_in[8];
    const float* b2 = (const float*)d_in[9];
    float* out = (float*)d_out;

    char* ws = (char*)d_ws;
    int*    pcnt  = (int*)(ws + WS_PCNT);
    int*    total = (int*)(ws + WS_TOTAL);
    int*    table = (int*)(ws + WS_TABLE);
    int*    plist = (int*)(ws + WS_PLIST);
    float2* pwts  = (float2*)(ws + WS_PWTS);
    unsigned short* W1p  = (unsigned short*)(ws + WS_W1P);
    unsigned short* W2p  = (unsigned short*)(ws + WS_W2P);
    unsigned short* ctxb = (unsigned short*)(ws + WS_CTXB);

    hipMemsetAsync(pcnt, 0, 64 * sizeof(int), stream);

    pre_kernel<<<1792 + NTOK, 256, 0, stream>>>(h, x, v, rw, rb, W1, W2,
                                                W1p, W2p, ctxb, out,
                                                pcnt, plist, pwts);
    prefix_kernel<<<1, 64, 0, stream>>>(pcnt, table, total);
    moe_kernel<<<576, 512, 0, stream>>>(x, v, mu, b1, b2, W1p, W2p, ctxb,
                                        pcnt, table, total, plist, pwts, out);
}

// Round 13
// 202.236 us; speedup vs baseline: 1.3551x; 1.0290x over previous
//
#include <hip/hip_runtime.h>
#include <math.h>

#define NTOK 8192
#define HD   2048
#define OD   1024
#define NE   8
#define CTXD 4096
#define CH   64

typedef short bf16x8 __attribute__((ext_vector_type(8)));
typedef float f32x4  __attribute__((ext_vector_type(4)));

static const size_t OFF_VN = (size_t)NTOK * OD;                 // v_next
static const size_t OFF_RP = 2 * (size_t)NTOK * OD;             // router_probs
static const size_t OFF_TI = OFF_RP + (size_t)NTOK * NE;        // top_k_idx
static const size_t OFF_TP = OFF_TI + (size_t)NTOK * 2;         // top_k_probs

// ---- ws byte offsets ----
#define WS_PCNT   0
#define WS_TOTAL  256
#define WS_TABLE  512
#define WS_PLIST  8192
#define WS_PWTS   (8192 + 64*NTOK*4)
#define WS_W1P    (WS_PWTS + 64*NTOK*8)
#define WS_W2P    (WS_W1P + NE*CTXD*CH*2)
#define WS_CTXB   (WS_W2P + NE*CH*3*OD*2)

__device__ __forceinline__ unsigned bfpack2(float a, float b) {
    unsigned ua = __float_as_uint(a), ub = __float_as_uint(b);
    ua = (ua + 0x7FFFu + ((ua >> 16) & 1u)) >> 16;
    ub = (ub + 0x7FFFu + ((ub >> 16) & 1u)) >> 16;
    return ua | (ub << 16);
}
__device__ __forceinline__ unsigned short bf1(float a) {
    unsigned ua = __float_as_uint(a);
    return (unsigned short)((ua + 0x7FFFu + ((ua >> 16) & 1u)) >> 16);
}
__device__ __forceinline__ float fsigmoid(float z) {
    return __fdividef(1.f, 1.f + __expf(-z));
}
__device__ __forceinline__ float fsoftplus(float z) {
    return fmaxf(z, 0.f) + __logf(1.f + __expf(-fabsf(z)));
}
__device__ __forceinline__ void gl_lds16(const void* g, void* l) {
    __builtin_amdgcn_global_load_lds(
        (const __attribute__((address_space(1))) void*)g,
        (__attribute__((address_space(3))) void*)l, 16, 0, 0);
}

// ---------------- fused pre-pass:
// blocks [0,1024): W1 -> W1p [8][512][64][8]
// blocks [1024,1792): W2 -> W2p [8][8][3072][8]
// blocks [1792,1792+2048): 4 tokens/block (wave-per-token): ctx->bf16 + router
__global__ __launch_bounds__(256) void pre_kernel(
    const float* __restrict__ h, const float* __restrict__ x,
    const float* __restrict__ v, const float* __restrict__ rw,
    const float* __restrict__ rb,
    const float* __restrict__ W1, const float* __restrict__ W2,
    unsigned short* __restrict__ W1p, unsigned short* __restrict__ W2p,
    unsigned short* __restrict__ ctxb,
    float* __restrict__ out,
    int* __restrict__ pcnt, int* __restrict__ plist, float2* __restrict__ pwts)
{
    int bb = blockIdx.x;
    int tid = threadIdx.x;
    if (bb < 1024) {
        int flat = bb * 256 + tid;
        int e = flat >> 15, rem = flat & 32767;
        int kb = rem >> 6, c = rem & 63;
        const float* src = W1 + (size_t)e * CTXD * CH + (size_t)kb * 8 * CH + c;
        uint4 o;
        o.x = bfpack2(src[0 * 64], src[1 * 64]);
        o.y = bfpack2(src[2 * 64], src[3 * 64]);
        o.z = bfpack2(src[4 * 64], src[5 * 64]);
        o.w = bfpack2(src[6 * 64], src[7 * 64]);
        *(uint4*)(W1p + (size_t)flat * 8) = o;
        return;
    }
    if (bb < 1792) {
        int flat = (bb - 1024) * 256 + tid;
        int e = flat / 24576, rem = flat - e * 24576;
        int kb = rem / 3072, c = rem - kb * 3072;
        const float* src = W2 + ((size_t)e * CH + kb * 8) * (3 * OD) + c;
        uint4 o;
        o.x = bfpack2(src[0 * 3072], src[1 * 3072]);
        o.y = bfpack2(src[2 * 3072], src[3 * 3072]);
        o.z = bfpack2(src[4 * 3072], src[5 * 3072]);
        o.w = bfpack2(src[6 * 3072], src[7 * 3072]);
        *(uint4*)(W2p + (size_t)flat * 8) = o;
        return;
    }
    // ---- ctx -> bf16 + fused router: one wave per token, no LDS/sync ----
    int lane = tid & 63;
    int wv   = tid >> 6;
    int t    = (bb - 1792) * 4 + wv;
    const float* hb = h + (size_t)t * HD;
    const float* xb = x + (size_t)t * OD;
    const float* vb = v + (size_t)t * OD;
    unsigned short* cb = ctxb + (size_t)t * CTXD;

    float r0=0.f,r1=0.f,r2=0.f,r3=0.f,r4=0.f,r5=0.f,r6=0.f,r7=0.f;

    #pragma unroll
    for (int i = 0; i < 16; i++) {
        int col = i * 256 + lane * 4;            // region uniform per i
        float4 f;
        if (i < 8)       f = *(const float4*)(hb + col);
        else if (i < 12) f = *(const float4*)(xb + (col - HD));
        else             f = *(const float4*)(vb + (col - HD - OD));
        // pack + store (coalesced uint2 = 4 bf16)
        uint2 pk = make_uint2(bfpack2(f.x, f.y), bfpack2(f.z, f.w));
        *(uint2*)(cb + col) = pk;
        if (i < 8) {
            // router partial: rows col..col+3 of rw (128B/lane, coalesced)
            const float4* wr = (const float4*)(rw + (size_t)col * 8);
            float4 wa0 = wr[0], wb0 = wr[1];
            float4 wa1 = wr[2], wb1 = wr[3];
            float4 wa2 = wr[4], wb2 = wr[5];
            float4 wa3 = wr[6], wb3 = wr[7];
            r0 = fmaf(f.x,wa0.x,fmaf(f.y,wa1.x,fmaf(f.z,wa2.x,fmaf(f.w,wa3.x,r0))));
            r1 = fmaf(f.x,wa0.y,fmaf(f.y,wa1.y,fmaf(f.z,wa2.y,fmaf(f.w,wa3.y,r1))));
            r2 = fmaf(f.x,wa0.z,fmaf(f.y,wa1.z,fmaf(f.z,wa2.z,fmaf(f.w,wa3.z,r2))));
            r3 = fmaf(f.x,wa0.w,fmaf(f.y,wa1.w,fmaf(f.z,wa2.w,fmaf(f.w,wa3.w,r3))));
            r4 = fmaf(f.x,wb0.x,fmaf(f.y,wb1.x,fmaf(f.z,wb2.x,fmaf(f.w,wb3.x,r4))));
            r5 = fmaf(f.x,wb0.y,fmaf(f.y,wb1.y,fmaf(f.z,wb2.y,fmaf(f.w,wb3.y,r5))));
            r6 = fmaf(f.x,wb0.z,fmaf(f.y,wb1.z,fmaf(f.z,wb2.z,fmaf(f.w,wb3.z,r6))));
            r7 = fmaf(f.x,wb0.w,fmaf(f.y,wb1.w,fmaf(f.z,wb2.w,fmaf(f.w,wb3.w,r7))));
        }
    }
    #pragma unroll
    for (int off = 32; off >= 1; off >>= 1) {
        r0 += __shfl_xor(r0, off); r1 += __shfl_xor(r1, off);
        r2 += __shfl_xor(r2, off); r3 += __shfl_xor(r3, off);
        r4 += __shfl_xor(r4, off); r5 += __shfl_xor(r5, off);
        r6 += __shfl_xor(r6, off); r7 += __shfl_xor(r7, off);
    }
    if (lane == 0) {
        float lg[8] = {r0+rb[0], r1+rb[1], r2+rb[2], r3+rb[3],
                       r4+rb[4], r5+rb[5], r6+rb[6], r7+rb[7]};
        float m = lg[0];
        #pragma unroll
        for (int e2 = 1; e2 < 8; e2++) m = fmaxf(m, lg[e2]);
        float p[8]; float s = 0.f;
        #pragma unroll
        for (int e2 = 0; e2 < 8; e2++) { p[e2] = expf(lg[e2] - m); s += p[e2]; }
        float inv = 1.f / s;
        #pragma unroll
        for (int e2 = 0; e2 < 8; e2++) {
            p[e2] *= inv;
            out[OFF_RP + (size_t)t * 8 + e2] = p[e2];
        }
        int e0 = 0;
        #pragma unroll
        for (int e2 = 1; e2 < 8; e2++) if (p[e2] > p[e0]) e0 = e2;
        int e1 = (e0 == 0) ? 1 : 0;
        #pragma unroll
        for (int e2 = 0; e2 < 8; e2++) {
            if (e2 == e0) continue;
            if (p[e2] > p[e1]) e1 = e2;
        }
        float s2 = p[e0] + p[e1];
        float w0 = p[e0] / s2, w1 = p[e1] / s2;
        out[OFF_TI + (size_t)t*2 + 0] = (float)e0;
        out[OFF_TI + (size_t)t*2 + 1] = (float)e1;
        out[OFF_TP + (size_t)t*2 + 0] = w0;
        out[OFF_TP + (size_t)t*2 + 1] = w1;
        int lo = min(e0, e1), hi = max(e0, e1);
        float wlo = (e0 < e1) ? w0 : w1;
        float whi = (e0 < e1) ? w1 : w0;
        int pid = lo * 8 + hi;
        int pos = atomicAdd(&pcnt[pid], 1);
        plist[pid * NTOK + pos] = t;
        pwts[pid * NTOK + pos] = make_float2(wlo, whi);
    }
}

// ---------------- prefix: pid counts -> dense 16-token tile table
__global__ void prefix_kernel(const int* __restrict__ pcnt,
                              int* __restrict__ table, int* __restrict__ total) {
    int tid = threadIdx.x;
    int cnt = pcnt[tid];
    int tiles = (cnt + 15) >> 4;
    int incl = tiles;
    #pragma unroll
    for (int off = 1; off < 64; off <<= 1) {
        int v = __shfl_up(incl, off);
        if (tid >= off) incl += v;
    }
    int base = incl - tiles;
    for (int i = 0; i < tiles; i++) table[base + i] = tid | (i << 6);
    if (tid == 63) *total = incl;
}

// ---------------- MoE: global_load_lds double-buffered stage-1, full-K acc
__global__ __launch_bounds__(512, 4) void moe_kernel(
    const float* __restrict__ x, const float* __restrict__ v,
    const float* __restrict__ mu,
    const float* __restrict__ b1, const float* __restrict__ b2,
    const unsigned short* __restrict__ W1p, const unsigned short* __restrict__ W2p,
    const unsigned short* __restrict__ ctxb,
    const int* __restrict__ pcnt, const int* __restrict__ table,
    const int* __restrict__ total, const int* __restrict__ plist,
    const float2* __restrict__ pwts, float* __restrict__ out)
{
    __shared__ unsigned short abuf[2][8192];     // dbuf A-tile chunk 16tok x 512c (2x16KB)
    __shared__ unsigned short hid_s[16 * 128];   // swizzled bf16 [16 tok][2*64]  4 KB
    __shared__ int    toks[16];
    __shared__ float2 tw[16];

    int bid = (blockIdx.x & 7) * 72 + (blockIdx.x >> 3);   // XCD-chunked, 576=8*72
    if (bid >= *total) return;
    int entry = table[bid];
    int pid = entry & 63;
    int start = (entry >> 6) * 16;
    int lo = pid >> 3, hi = pid & 7;
    int cnt = pcnt[pid];
    int nt = cnt - start; if (nt > 16) nt = 16;

    int tid = threadIdx.x;
    if (tid < 16) {
        int idx = start + (tid < nt ? tid : 0);
        toks[tid] = plist[pid * NTOK + idx];
        tw[tid]   = pwts[pid * NTOK + idx];
    }
    __syncthreads();

    int lane = tid & 63, w = tid >> 6;           // 8 waves
    int l15 = lane & 15, lq = lane >> 4;

    // stage-1 wave roles: (expert slot, col-group); full-K accumulation
    int s1s = w >> 2;                            // 0 = lo, 1 = hi
    int cg  = w & 3;                             // 16-col group within expert's 64
    int myE = s1s ? hi : lo;
    int colw = cg * 16 + l15;
    const unsigned short* W1e = W1p + (size_t)myE * (CTXD * CH);

    // staging: per chunk (512 cols), wave w stages token rows 2w, 2w+1
    // LDS linear; global src pre-swizzled so reads can XOR-deswizzle (rule #21)
    int wv2 = w * 2;

#define STAGE(KC, BUF) do {                                                    \
        _Pragma("unroll")                                                      \
        for (int j = 0; j < 2; j++) {                                          \
            int r_ = wv2 + j;                                                  \
            int tok_ = toks[r_];                                               \
            int soff_ = ((lane * 16) ^ ((r_ & 7) << 4)) >> 1;                  \
            const unsigned short* gs_ = ctxb + (size_t)tok_ * CTXD             \
                                        + (KC) * 512 + soff_;                  \
            gl_lds16(gs_, (char*)abuf[BUF] + w * 2048 + j * 1024);             \
        }                                                                      \
    } while (0)

    f32x4 acc = {0.f, 0.f, 0.f, 0.f};

    STAGE(0, 0);
    __syncthreads();                              // vmcnt drain -> buf0 ready
    for (int kc = 0; kc < 8; kc++) {
        int cur = kc & 1;
        if (kc < 7) STAGE(kc + 1, cur ^ 1);       // async DMA, hides under compute
        #pragma unroll
        for (int ks = 0; ks < 16; ks++) {
            int phys = (ks * 64 + lq * 16) ^ ((l15 & 7) << 4);
            bf16x8 a = *(const bf16x8*)((const char*)abuf[cur] + l15 * 1024 + phys);
            int kb = kc * 64 + ks * 4 + lq;
            bf16x8 b = *(const bf16x8*)(W1e + ((size_t)kb * 64 + colw) * 8);
            acc = __builtin_amdgcn_mfma_f32_16x16x32_bf16(a, b, acc, 0, 0, 0);
        }
        __syncthreads();                          // drains stage DMA + guards dbuf
    }
#undef STAGE

    // relu + bias -> hid LDS (bf16, swizzled). C layout: col=l15, row=lq*4+i
    {
        float b1v = b1[myE * CH + colw];
        int colh = s1s * 64 + colw;
        #pragma unroll
        for (int i = 0; i < 4; i++) {
            int r0 = lq * 4 + i;
            float hv = acc[i] + b1v; hv = hv > 0.f ? hv : 0.f;
            int by = (r0 * 256 + colh * 2) ^ ((r0 & 7) << 4);
            *(unsigned short*)((char*)hid_s + by) = bf1(hv);
        }
    }
    __syncthreads();

    // ---- stage 2: wave w owns o-band [w*128, w*128+128)
    bf16x8 af[2][2];
    #pragma unroll
    for (int s = 0; s < 2; s++)
        #pragma unroll
        for (int ks = 0; ks < 2; ks++) {
            int col = s * 64 + ks * 32 + lq * 8;
            int by = (l15 * 256 + col * 2) ^ ((l15 & 7) << 4);
            af[s][ks] = *(const bf16x8*)((const char*)hid_s + by);
        }

    const unsigned short* W2lo = W2p + (size_t)lo * (CH * 3 * OD);
    const unsigned short* W2hi = W2p + (size_t)hi * (CH * 3 * OD);
    const float* b2lo = b2 + (size_t)lo * 3072;
    const float* b2hi = b2 + (size_t)hi * 3072;

    int   tok_r[4];
    float twx[4], twy[4];
    #pragma unroll
    for (int i = 0; i < 4; i++) {
        int trow = lq * 4 + i;
        tok_r[i] = toks[trow];
        float2 t2 = tw[trow];
        twx[i] = t2.x; twy[i] = t2.y;
    }

    for (int ot = 0; ot < 8; ot++) {
        int o = w * 128 + ot * 16 + l15;
        float xo[4], vo[4];
        #pragma unroll
        for (int i = 0; i < 4; i++) {
            size_t off = (size_t)tok_r[i] * OD + o;
            xo[i] = x[off];
            vo[i] = v[off];
        }
        float muo = mu[o];
        float accVN[4] = {0.f,0.f,0.f,0.f};
        float accGV[4] = {0.f,0.f,0.f,0.f};

        #pragma unroll
        for (int s = 0; s < 2; s++) {
            const unsigned short* W2e = s ? W2hi : W2lo;
            const float* b2e = s ? b2hi : b2lo;
            f32x4 aA = {0.f,0.f,0.f,0.f};
            f32x4 aB = {0.f,0.f,0.f,0.f};
            f32x4 aG = {0.f,0.f,0.f,0.f};
            #pragma unroll
            for (int ks = 0; ks < 2; ks++) {
                int kb = ks * 4 + lq;
                bf16x8 wA = *(const bf16x8*)(W2e + ((size_t)kb * 3072 + o) * 8);
                bf16x8 wB = *(const bf16x8*)(W2e + ((size_t)kb * 3072 + OD + o) * 8);
                bf16x8 wG = *(const bf16x8*)(W2e + ((size_t)kb * 3072 + 2 * OD + o) * 8);
                aA = __builtin_amdgcn_mfma_f32_16x16x32_bf16(af[s][ks], wA, aA, 0, 0, 0);
                aB = __builtin_amdgcn_mfma_f32_16x16x32_bf16(af[s][ks], wB, aB, 0, 0, 0);
                aG = __builtin_amdgcn_mfma_f32_16x16x32_bf16(af[s][ks], wG, aG, 0, 0, 0);
            }
            float ba = b2e[o], bb = b2e[OD + o], bg = b2e[2 * OD + o];
            #pragma unroll
            for (int i = 0; i < 4; i++) {
                float za = aA[i] + ba;
                float zb = aB[i] + bb;
                float zg = aG[i] + bg;
                float alpha = fsigmoid(za);
                float beta  = fsoftplus(zb);
                float gate  = fsigmoid(zg);
                float ws = s ? twy[i] : twx[i];
                float vn_s = alpha * vo[i] - beta * (xo[i] - muo);
                accVN[i] += ws * vn_s;
                accGV[i] += ws * gate * vn_s;
            }
        }
        #pragma unroll
        for (int i = 0; i < 4; i++) {
            if (lq * 4 + i < nt) {
                size_t off = (size_t)tok_r[i] * OD + o;
                out[off]          = xo[i] + 0.1f * accGV[i];
                out[OFF_VN + off] = accVN[i];
            }
        }
    }
}

extern "C" void kernel_launch(void* const* d_in, const int* in_sizes, int n_in,
                              void* d_out, int out_size, void* d_ws, size_t ws_size,
                              hipStream_t stream)
{
    (void)in_sizes; (void)n_in; (void)out_size; (void)ws_size;
    const float* h  = (const float*)d_in[0];
    const float* x  = (const float*)d_in[1];
    const float* v  = (const float*)d_in[2];
    const float* rw = (const float*)d_in[3];
    const float* rb = (const float*)d_in[4];
    const float* mu = (const float*)d_in[5];
    const float* W1 = (const float*)d_in[6];
    const float* b1 = (const float*)d_in[7];
    const float* W2 = (const float*)d_in[8];
    const float* b2 = (const float*)d_in[9];
    float* out = (float*)d_out;

    char* ws = (char*)d_ws;
    int*    pcnt  = (int*)(ws + WS_PCNT);
    int*    total = (int*)(ws + WS_TOTAL);
    int*    table = (int*)(ws + WS_TABLE);
    int*    plist = (int*)(ws + WS_PLIST);
    float2* pwts  = (float2*)(ws + WS_PWTS);
    unsigned short* W1p  = (unsigned short*)(ws + WS_W1P);
    unsigned short* W2p  = (unsigned short*)(ws + WS_W2P);
    unsigned short* ctxb = (unsigned short*)(ws + WS_CTXB);

    hipMemsetAsync(pcnt, 0, 64 * sizeof(int), stream);

    pre_kernel<<<1792 + 2048, 256, 0, stream>>>(h, x, v, rw, rb, W1, W2,
                                                W1p, W2p, ctxb, out,
                                                pcnt, plist, pwts);
    prefix_kernel<<<1, 64, 0, stream>>>(pcnt, table, total);
    moe_kernel<<<576, 512, 0, stream>>>(x, v, mu, b1, b2, W1p, W2p, ctxb,
                                        pcnt, table, total, plist, pwts, out);
}